// Round 6
// baseline (132.569 us; speedup 1.0000x reference)
//
#include <hip/hip_runtime.h>

#define NQ 22
#define DIM (1 << NQ)
#define TILE 2048
#define LOG_TILE 11

typedef float f32x4_t __attribute__((ext_vector_type(4)));

// Precompute B[l] = sum over pairs p>q (LSB positions 0..10) both set in l of
// U[(21-p)*22 + (21-q)].  2048 entries, written to workspace (8 KB).
__global__ __launch_bounds__(256) void ryd_precompute_B(const float* __restrict__ U,
                                                        float* __restrict__ Btab) {
    int t = blockIdx.x * blockDim.x + threadIdx.x;  // 0..2047
    __shared__ float Us[NQ * NQ];
    for (int i = threadIdx.x; i < NQ * NQ; i += blockDim.x) Us[i] = U[i];
    __syncthreads();
    float b = 0.f;
    #pragma unroll
    for (int p = 1; p <= 10; ++p) {
        if ((t >> p) & 1) {
            #pragma unroll
            for (int q = 0; q < p; ++q) {
                if ((t >> q) & 1) b += Us[(21 - p) * NQ + (21 - q)];
            }
        }
    }
    Btab[t] = b;
}

#define ACC8(a0, a1, b0, b1)                                              \
    do {                                                                  \
        ar[0] += (a0).x; ar[1] += (a0).y; ar[2] += (a0).z; ar[3] += (a0).w; \
        ar[4] += (a1).x; ar[5] += (a1).y; ar[6] += (a1).z; ar[7] += (a1).w; \
        ai[0] += (b0).x; ai[1] += (b0).y; ai[2] += (b0).z; ai[3] += (b0).w; \
        ai[4] += (b1).x; ai[5] += (b1).y; ai[6] += (b1).z; ai[7] += (b1).w; \
    } while (0)

// LDS chunk swizzle (16B granularity): spreads one wave's ds_read_b128 lanes
// across all 8 bank groups.
__device__ __forceinline__ int swz(int c) { return c ^ ((c >> 3) & 1); }

// ---------------------------------------------------------------------------
// Pass A: per 2048-tile — register flips (bits 0..2), LDS flips (bits 3..10),
// full diagonal.  Pure streaming: ONE global load-wait point per block.
// NT stores: out must NOT sit dirty in this XCD's L2 — pass B reads it in
// column pattern from all XCDs, and cross-XCD dirty-line reads are the slow
// path (R5 regression).  NT pushes the lines out clean to L3/HBM.
// ---------------------------------------------------------------------------
__global__ __launch_bounds__(256) void ryd_rows(
    const float* __restrict__ sr_g, const float* __restrict__ si_g,
    const float* __restrict__ rabi, const float* __restrict__ detune,
    const float* __restrict__ U, const float* __restrict__ Btab,
    float* __restrict__ out) {
    __shared__ float4 srv[TILE / 4];   // swizzled 16B chunks, 8 KB
    __shared__ float4 siv[TILE / 4];   // 8 KB
    __shared__ float AD[12];  // AD[0..10] = Dq[q] (cross sums), AD[11] = A(h)

    const int h = blockIdx.x;        // high 11 bits of the basis index
    const int tid = threadIdx.x;     // 0..255
    const int m0 = tid << 3;         // local element base (this thread owns 8)
    const int base = h << LOG_TILE;  // global tile base

    float4 r0 = *(const float4*)(sr_g + base + m0);
    float4 r1 = *(const float4*)(sr_g + base + m0 + 4);
    float4 i0 = *(const float4*)(si_g + base + m0);
    float4 i1 = *(const float4*)(si_g + base + m0 + 4);

    float4 B0 = *(const float4*)(Btab + m0);
    float4 B1 = *(const float4*)(Btab + m0 + 4);

    srv[swz(2 * tid)]     = r0;
    srv[swz(2 * tid + 1)] = r1;
    siv[swz(2 * tid)]     = i0;
    siv[swz(2 * tid + 1)] = i1;

    // Threads 0..10: Dq[q] = sum_{hp set in h} U[(10-hp)*22 + (21-q)]
    // Thread 11:     A(h)  = sum over pairs hp>hq set in h of U[(10-hp)*22+(10-hq)]
    if (tid < 11) {
        int q = tid;
        float d = 0.f;
        #pragma unroll
        for (int hp = 0; hp <= 10; ++hp)
            if ((h >> hp) & 1) d += U[(10 - hp) * NQ + (21 - q)];
        AD[q] = d;
    } else if (tid == 11) {
        float a = 0.f;
        #pragma unroll
        for (int hp = 1; hp <= 10; ++hp) {
            if ((h >> hp) & 1) {
                #pragma unroll
                for (int hq = 0; hq < hp; ++hq)
                    if ((h >> hq) & 1) a += U[(10 - hp) * NQ + (10 - hq)];
            }
        }
        AD[11] = a;
    }

    float pr[8]  = {r0.x, r0.y, r0.z, r0.w, r1.x, r1.y, r1.z, r1.w};
    float pi_[8] = {i0.x, i0.y, i0.z, i0.w, i1.x, i1.y, i1.z, i1.w};

    __syncthreads();

    // Flip bits 0..2: partners in this thread's own registers.
    float ar[8], ai[8];
    #pragma unroll
    for (int e = 0; e < 8; ++e) {
        ar[e] = pr[e ^ 1] + pr[e ^ 2] + pr[e ^ 4];
        ai[e] = pi_[e ^ 1] + pi_[e ^ 2] + pi_[e ^ 4];
    }

    // Flip bits 3..10: partner 8-blocks inside the LDS tile (swizzled b128).
    #pragma unroll
    for (int jj = 0; jj < 8; ++jj) {
        int p = tid ^ (1 << jj);
        float4 a0 = srv[swz(2 * p)];
        float4 a1 = srv[swz(2 * p + 1)];
        float4 b0 = siv[swz(2 * p)];
        float4 b1 = siv[swz(2 * p + 1)];
        ACC8(a0, a1, b0, b1);
    }

    // Diagonal: diag(b) = A + B[l] + sum_{q set in l} Dq[q] - det*popc(b)
    const float det = detune[0];
    const float hrabi = 0.5f * rabi[0];
    float Dq0 = AD[0] - det;
    float Dq1 = AD[1] - det;
    float Dq2 = AD[2] - det;
    float diagBase = AD[11] - det * (float)__popc((unsigned)h);
    #pragma unroll
    for (int j = 0; j < 8; ++j)
        if ((tid >> j) & 1) diagBase += AD[j + 3] - det;

    float Bv[8] = {B0.x, B0.y, B0.z, B0.w, B1.x, B1.y, B1.z, B1.w};

    float orv[8], oiv[8];
    #pragma unroll
    for (int e = 0; e < 8; ++e) {
        float d = diagBase + Bv[e];
        if (e & 1) d += Dq0;
        if (e & 2) d += Dq1;
        if (e & 4) d += Dq2;
        orv[e] = hrabi * ar[e] + d * pr[e];
        oiv[e] = hrabi * ai[e] + d * pi_[e];
    }

    f32x4_t o0 = {orv[0], orv[1], orv[2], orv[3]};
    f32x4_t o1 = {orv[4], orv[5], orv[6], orv[7]};
    f32x4_t o2 = {oiv[0], oiv[1], oiv[2], oiv[3]};
    f32x4_t o3 = {oiv[4], oiv[5], oiv[6], oiv[7]};
    __builtin_nontemporal_store(o0, (f32x4_t*)(out + base + m0));
    __builtin_nontemporal_store(o1, (f32x4_t*)(out + base + m0 + 4));
    __builtin_nontemporal_store(o2, (f32x4_t*)(out + DIM + base + m0));
    __builtin_nontemporal_store(o3, (f32x4_t*)(out + DIM + base + m0 + 4));
}

// ---------------------------------------------------------------------------
// Pass B: flips of the high 11 bits.  psi viewed as [hi=2048][lo=2048]; each
// block owns a 2048-row x 16-col slice of ONE array (re or im): load into LDS
// (one full 64B line per row, perfectly partitioned across blocks), prefetch
// the 8 RMW 'cur' values BEFORE the barrier (address-independent of LDS), do
// all 11 hi-bit flips as LDS b128 reads, RMW-add hrabi*S into out (NT).
// ---------------------------------------------------------------------------
__global__ __launch_bounds__(1024, 4) void ryd_cols(
    const float* __restrict__ sr_g, const float* __restrict__ si_g,
    const float* __restrict__ rabi, float* __restrict__ out) {
    __shared__ f32x4_t L[TILE * 4];  // [row 0..2047][cv 0..3], 128 KB

    const int b = blockIdx.x;        // 0..255
    const int A = b & 1;             // 0 = real, 1 = imag
    const int C0 = (b >> 1) << 4;    // column base (multiple of 16 -> 64B lines)
    const float* __restrict__ src = A ? si_g : sr_g;
    float* __restrict__ dst = out + (A ? DIM : 0);
    const int t = threadIdx.x;       // 0..1023
    const float hrabi = 0.5f * rabi[0];

    // Stage: cell n = (row r, colvec cv).  4 lanes cover one full 64B line.
    #pragma unroll
    for (int k = 0; k < 8; ++k) {
        int n = t + (k << 10);
        int r = n >> 2, cv = n & 3;
        L[(r << 2) + cv] = *(const f32x4_t*)(src + (r << 11) + C0 + (cv << 2));
    }

    // Prefetch the 8 RMW reads of out: in flight across the barrier drain, so
    // the compute phase never waits on global latency.
    f32x4_t cur[8];
    #pragma unroll
    for (int k = 0; k < 8; ++k) {
        int n = t + (k << 10);
        int r = n >> 2, cv = n & 3;
        cur[k] = __builtin_nontemporal_load(
            (const f32x4_t*)(dst + (r << 11) + C0 + (cv << 2)));
    }

    __syncthreads();

    // Flip-sum over hi bits 0..10 (global bits 11..21), then RMW into out.
    #pragma unroll
    for (int k = 0; k < 8; ++k) {
        int n = t + (k << 10);
        int r = n >> 2, cv = n & 3;
        f32x4_t acc = L[((r ^ 1) << 2) + cv];
        #pragma unroll
        for (int j = 1; j < 11; ++j)
            acc += L[(((r ^ (1 << j)) << 2)) + cv];
        f32x4_t res = cur[k] + acc * hrabi;
        __builtin_nontemporal_store(res, (f32x4_t*)(dst + (r << 11) + C0 + (cv << 2)));
    }
}

extern "C" void kernel_launch(void* const* d_in, const int* in_sizes, int n_in,
                              void* d_out, int out_size, void* d_ws, size_t ws_size,
                              hipStream_t stream) {
    const float* state_real = (const float*)d_in[0];
    const float* state_imag = (const float*)d_in[1];
    const float* rabi       = (const float*)d_in[2];
    const float* detune     = (const float*)d_in[3];
    const float* U          = (const float*)d_in[4];
    float* Btab = (float*)d_ws;  // 2048 floats = 8 KB
    float* out  = (float*)d_out;

    ryd_precompute_B<<<TILE / 256, 256, 0, stream>>>(U, Btab);
    ryd_rows<<<DIM / TILE, 256, 0, stream>>>(state_real, state_imag, rabi, detune,
                                             U, Btab, out);
    ryd_cols<<<256, 1024, 0, stream>>>(state_real, state_imag, rabi, out);
}

// Round 7
// 131.597 us; speedup vs baseline: 1.0074x; 1.0074x over previous
//
#include <hip/hip_runtime.h>

#define NQ 22
#define DIM (1 << NQ)
#define TILE 2048
#define LOG_TILE 11

typedef float f32x4_t __attribute__((ext_vector_type(4)));

// Precompute B[l] = sum over pairs p>q (LSB positions 0..10) both set in l of
// U[(21-p)*22 + (21-q)].  2048 entries, written to workspace (8 KB).
__global__ __launch_bounds__(256) void ryd_precompute_B(const float* __restrict__ U,
                                                        float* __restrict__ Btab) {
    int t = blockIdx.x * blockDim.x + threadIdx.x;  // 0..2047
    __shared__ float Us[NQ * NQ];
    for (int i = threadIdx.x; i < NQ * NQ; i += blockDim.x) Us[i] = U[i];
    __syncthreads();
    float b = 0.f;
    #pragma unroll
    for (int p = 1; p <= 10; ++p) {
        if ((t >> p) & 1) {
            #pragma unroll
            for (int q = 0; q < p; ++q) {
                if ((t >> q) & 1) b += Us[(21 - p) * NQ + (21 - q)];
            }
        }
    }
    Btab[t] = b;
}

#define ACC8(a0, a1, b0, b1)                                              \
    do {                                                                  \
        ar[0] += (a0).x; ar[1] += (a0).y; ar[2] += (a0).z; ar[3] += (a0).w; \
        ar[4] += (a1).x; ar[5] += (a1).y; ar[6] += (a1).z; ar[7] += (a1).w; \
        ai[0] += (b0).x; ai[1] += (b0).y; ai[2] += (b0).z; ai[3] += (b0).w; \
        ai[4] += (b1).x; ai[5] += (b1).y; ai[6] += (b1).z; ai[7] += (b1).w; \
    } while (0)

// LDS chunk swizzle (16B granularity): spreads one wave's ds_read_b128 lanes
// across all 8 bank groups.
__device__ __forceinline__ int swz(int c) { return c ^ ((c >> 3) & 1); }

// ---------------------------------------------------------------------------
// Pass B (runs FIRST, pure writes): flips of the high 11 bits.
// psi viewed as [hi=2048][lo=2048].  Each block owns 1024 rows x 16 cols of
// ONE array (64 KB LDS -> 2 blocks/CU + 2 generations: stage/compute/write
// phases of different blocks overlap — the R5/R6 serial-phase fix).
// Hi bits 0..9 butterflied in LDS; bit 10 (row^1024) streamed from global
// into registers (L2/L3-warm second touch), in flight across the barrier.
// out = hrabi * S_hi  (no RMW read; pass A adds the rest afterward).
// ---------------------------------------------------------------------------
__global__ __launch_bounds__(512, 4) void ryd_cols(
    const float* __restrict__ sr_g, const float* __restrict__ si_g,
    const float* __restrict__ rabi, float* __restrict__ out) {
    __shared__ f32x4_t L[1024 * 4];   // [row 0..1023][cv 0..3], 64 KB

    const int b = blockIdx.x;         // 0..511
    const int A = b & 1;              // 0 = real, 1 = imag
    const int half = (b >> 1) & 1;    // row half: R0 = half*1024
    const int C0 = (b >> 2) << 4;     // column base (16 cols = one 64B line)
    const int R0 = half << 10;
    const float* __restrict__ src = A ? si_g : sr_g;
    float* __restrict__ dst = out + (A ? DIM : 0);
    const int t = threadIdx.x;        // 0..511
    const float hrabi = 0.5f * rabi[0];

    // Stage own half-slice: chunk n = (row r, colvec cv); 4 lanes = one line.
    #pragma unroll
    for (int k = 0; k < 8; ++k) {
        int n = t + (k << 9);
        int r = n >> 2, cv = n & 3;
        L[(r << 2) + cv] =
            *(const f32x4_t*)(src + ((R0 + r) << 11) + C0 + (cv << 2));
    }

    // Bit-10 flip partner (other 1024-row half): stream into registers,
    // stays in flight across the barrier drain.
    f32x4_t pp[8];
    #pragma unroll
    for (int k = 0; k < 8; ++k) {
        int n = t + (k << 9);
        int r = n >> 2, cv = n & 3;
        pp[k] = *(const f32x4_t*)(src + (((R0 ^ 1024) + r) << 11) + C0 + (cv << 2));
    }

    __syncthreads();

    // Butterfly over hi bits 0..9 in LDS + register partner term, pure NT write.
    #pragma unroll
    for (int k = 0; k < 8; ++k) {
        int n = t + (k << 9);
        int r = n >> 2, cv = n & 3;
        f32x4_t acc = pp[k];
        #pragma unroll
        for (int j = 0; j < 10; ++j)
            acc += L[((r ^ (1 << j)) << 2) + cv];
        f32x4_t res = acc * hrabi;
        __builtin_nontemporal_store(
            res, (f32x4_t*)(dst + ((R0 + r) << 11) + C0 + (cv << 2)));
    }
}

// ---------------------------------------------------------------------------
// Pass A (runs SECOND): per 2048-tile — register flips (bits 0..2), LDS flips
// (bits 3..10), full diagonal, RMW-add onto pass B's S_hi already in out.
// All global access row-contiguous; one load-wait point per block.
// ---------------------------------------------------------------------------
__global__ __launch_bounds__(256) void ryd_rows(
    const float* __restrict__ sr_g, const float* __restrict__ si_g,
    const float* __restrict__ rabi, const float* __restrict__ detune,
    const float* __restrict__ U, const float* __restrict__ Btab,
    float* __restrict__ out) {
    __shared__ float4 srv[TILE / 4];   // swizzled 16B chunks, 8 KB
    __shared__ float4 siv[TILE / 4];   // 8 KB
    __shared__ float AD[12];  // AD[0..10] = Dq[q] (cross sums), AD[11] = A(h)

    const int h = blockIdx.x;        // high 11 bits of the basis index
    const int tid = threadIdx.x;     // 0..255
    const int m0 = tid << 3;         // local element base (this thread owns 8)
    const int base = h << LOG_TILE;  // global tile base

    float4 r0 = *(const float4*)(sr_g + base + m0);
    float4 r1 = *(const float4*)(sr_g + base + m0 + 4);
    float4 i0 = *(const float4*)(si_g + base + m0);
    float4 i1 = *(const float4*)(si_g + base + m0 + 4);

    float4 B0 = *(const float4*)(Btab + m0);
    float4 B1 = *(const float4*)(Btab + m0 + 4);

    // RMW read of pass B's S_hi contribution (row-contiguous, prefetched here).
    float4 z0 = *(const float4*)(out + base + m0);
    float4 z1 = *(const float4*)(out + base + m0 + 4);
    float4 z2 = *(const float4*)(out + DIM + base + m0);
    float4 z3 = *(const float4*)(out + DIM + base + m0 + 4);

    srv[swz(2 * tid)]     = r0;
    srv[swz(2 * tid + 1)] = r1;
    siv[swz(2 * tid)]     = i0;
    siv[swz(2 * tid + 1)] = i1;

    // Threads 0..10: Dq[q] = sum_{hp set in h} U[(10-hp)*22 + (21-q)]
    // Thread 11:     A(h)  = sum over pairs hp>hq set in h of U[(10-hp)*22+(10-hq)]
    if (tid < 11) {
        int q = tid;
        float d = 0.f;
        #pragma unroll
        for (int hp = 0; hp <= 10; ++hp)
            if ((h >> hp) & 1) d += U[(10 - hp) * NQ + (21 - q)];
        AD[q] = d;
    } else if (tid == 11) {
        float a = 0.f;
        #pragma unroll
        for (int hp = 1; hp <= 10; ++hp) {
            if ((h >> hp) & 1) {
                #pragma unroll
                for (int hq = 0; hq < hp; ++hq)
                    if ((h >> hq) & 1) a += U[(10 - hp) * NQ + (10 - hq)];
            }
        }
        AD[11] = a;
    }

    float pr[8]  = {r0.x, r0.y, r0.z, r0.w, r1.x, r1.y, r1.z, r1.w};
    float pi_[8] = {i0.x, i0.y, i0.z, i0.w, i1.x, i1.y, i1.z, i1.w};

    __syncthreads();

    // Flip bits 0..2: partners in this thread's own registers.
    float ar[8], ai[8];
    #pragma unroll
    for (int e = 0; e < 8; ++e) {
        ar[e] = pr[e ^ 1] + pr[e ^ 2] + pr[e ^ 4];
        ai[e] = pi_[e ^ 1] + pi_[e ^ 2] + pi_[e ^ 4];
    }

    // Flip bits 3..10: partner 8-blocks inside the LDS tile (swizzled b128).
    #pragma unroll
    for (int jj = 0; jj < 8; ++jj) {
        int p = tid ^ (1 << jj);
        float4 a0 = srv[swz(2 * p)];
        float4 a1 = srv[swz(2 * p + 1)];
        float4 b0 = siv[swz(2 * p)];
        float4 b1 = siv[swz(2 * p + 1)];
        ACC8(a0, a1, b0, b1);
    }

    // Diagonal: diag(b) = A + B[l] + sum_{q set in l} Dq[q] - det*popc(b)
    const float det = detune[0];
    const float hrabi = 0.5f * rabi[0];
    float Dq0 = AD[0] - det;
    float Dq1 = AD[1] - det;
    float Dq2 = AD[2] - det;
    float diagBase = AD[11] - det * (float)__popc((unsigned)h);
    #pragma unroll
    for (int j = 0; j < 8; ++j)
        if ((tid >> j) & 1) diagBase += AD[j + 3] - det;

    float Bv[8] = {B0.x, B0.y, B0.z, B0.w, B1.x, B1.y, B1.z, B1.w};
    float zr[8] = {z0.x, z0.y, z0.z, z0.w, z1.x, z1.y, z1.z, z1.w};
    float zi[8] = {z2.x, z2.y, z2.z, z2.w, z3.x, z3.y, z3.z, z3.w};

    float orv[8], oiv[8];
    #pragma unroll
    for (int e = 0; e < 8; ++e) {
        float d = diagBase + Bv[e];
        if (e & 1) d += Dq0;
        if (e & 2) d += Dq1;
        if (e & 4) d += Dq2;
        orv[e] = zr[e] + hrabi * ar[e] + d * pr[e];
        oiv[e] = zi[e] + hrabi * ai[e] + d * pi_[e];
    }

    f32x4_t o0 = {orv[0], orv[1], orv[2], orv[3]};
    f32x4_t o1 = {orv[4], orv[5], orv[6], orv[7]};
    f32x4_t o2 = {oiv[0], oiv[1], oiv[2], oiv[3]};
    f32x4_t o3 = {oiv[4], oiv[5], oiv[6], oiv[7]};
    __builtin_nontemporal_store(o0, (f32x4_t*)(out + base + m0));
    __builtin_nontemporal_store(o1, (f32x4_t*)(out + base + m0 + 4));
    __builtin_nontemporal_store(o2, (f32x4_t*)(out + DIM + base + m0));
    __builtin_nontemporal_store(o3, (f32x4_t*)(out + DIM + base + m0 + 4));
}

extern "C" void kernel_launch(void* const* d_in, const int* in_sizes, int n_in,
                              void* d_out, int out_size, void* d_ws, size_t ws_size,
                              hipStream_t stream) {
    const float* state_real = (const float*)d_in[0];
    const float* state_imag = (const float*)d_in[1];
    const float* rabi       = (const float*)d_in[2];
    const float* detune     = (const float*)d_in[3];
    const float* U          = (const float*)d_in[4];
    float* Btab = (float*)d_ws;  // 2048 floats = 8 KB
    float* out  = (float*)d_out;

    ryd_precompute_B<<<TILE / 256, 256, 0, stream>>>(U, Btab);
    // Pass B first: out = hrabi * S_hi (pure writes).
    ryd_cols<<<512, 512, 0, stream>>>(state_real, state_imag, rabi, out);
    // Pass A second: out += diag*psi + hrabi * S_lo (row-contiguous RMW).
    ryd_rows<<<DIM / TILE, 256, 0, stream>>>(state_real, state_imag, rabi, detune,
                                             U, Btab, out);
}